// Round 10
// baseline (2580.930 us; speedup 1.0000x reference)
//
#include <hip/hip_runtime.h>
#include <hip/hip_bf16.h>
#include <math.h>

#define HH 32
#define LL 3
#define DS 512
#define DID 128
#define DSTEER 1664
#define DHID 2048
#define HDQ 1024
#define BHROWS 32768

typedef __attribute__((ext_vector_type(8))) short short8;
typedef __attribute__((ext_vector_type(4))) float f32x4;

typedef const __attribute__((address_space(1))) unsigned int* gptr_t;
typedef __attribute__((address_space(3))) unsigned int* lptr_t;

#define BAR() __builtin_amdgcn_s_barrier()
#define SB()  __builtin_amdgcn_sched_barrier(0)
#define VMCNT8() asm volatile("s_waitcnt vmcnt(8)")
#define VMCNT2() asm volatile("s_waitcnt vmcnt(2)")
#define VMCNT0() asm volatile("s_waitcnt vmcnt(0)")

__device__ __forceinline__ unsigned short f2bf(float f) {
  union { float f; unsigned int u; } x; x.f = f;
  unsigned int r = (x.u + 0x7FFFu + ((x.u >> 16) & 1u)) >> 16;
  return (unsigned short)r;
}
__device__ __forceinline__ unsigned int pk2(float a, float b) {
  return (unsigned int)f2bf(a) | ((unsigned int)f2bf(b) << 16);
}
__device__ __forceinline__ float gelu_exact(float v) {
  return 0.5f * v * (1.0f + erff(v * 0.70710678118654752440f));
}

// ---------- fp32 -> bf16 bulk convert ----------
__global__ void cvt_bf16_kernel(const float4* __restrict__ in, uint2* __restrict__ out, long n4) {
  long i = (long)blockIdx.x * blockDim.x + threadIdx.x;
  long stride = (long)gridDim.x * blockDim.x;
  for (; i < n4; i += stride) {
    float4 v = in[i];
    uint2 o; o.x = pk2(v.x, v.y); o.y = pk2(v.z, v.w);
    out[i] = o;
  }
}

// ---------- batched transpose + convert: fp32 [R][C] -> bf16 [C][R] ----------
__global__ void transpose_cvt_kernel(const float* __restrict__ in, long long in_bstride,
                                     unsigned short* __restrict__ out, long long out_bstride,
                                     int R, int C) {
  __shared__ float t[64][33];
  const int r0 = blockIdx.y * 32;
  const int c0 = blockIdx.x * 64;
  const float* bin = in + (long long)blockIdx.z * in_bstride;
  unsigned short* bout = out + (long long)blockIdx.z * out_bstride;
  const int tid = threadIdx.x;
  const int col = tid & 63, rr = tid >> 6;
  #pragma unroll
  for (int j = 0; j < 8; j++) {
    int r = j * 4 + rr;
    t[col][r] = bin[(size_t)(r0 + r) * C + c0 + col];
  }
  __syncthreads();
  const int rq = (tid & 7) * 4;
  const int cc = tid >> 3;
  #pragma unroll
  for (int j = 0; j < 2; j++) {
    int c = j * 32 + cc;
    float v0 = t[c][rq], v1 = t[c][rq + 1], v2 = t[c][rq + 2], v3 = t[c][rq + 3];
    uint2 o; o.x = pk2(v0, v1); o.y = pk2(v2, v3);
    *(uint2*)&bout[(size_t)(c0 + c) * R + r0 + rq] = o;
  }
}

// ---------- RMS-norm + scale -> bf16 ----------
__global__ void rms_scale_kernel(const float* __restrict__ h,
                                 const float* __restrict__ norm_w,
                                 unsigned short* __restrict__ xn, int layer) {
  int gw = (int)((blockIdx.x * blockDim.x + threadIdx.x) >> 6);
  int lane = threadIdx.x & 63;
  if (gw >= BHROWS) return;
  int head = gw & (HH - 1);
  const float4* hr = (const float4*)(h + (size_t)gw * DS);
  float4 v0 = hr[lane * 2], v1 = hr[lane * 2 + 1];
  float ss = v0.x*v0.x + v0.y*v0.y + v0.z*v0.z + v0.w*v0.w
           + v1.x*v1.x + v1.y*v1.y + v1.z*v1.z + v1.w*v1.w;
  #pragma unroll
  for (int off = 32; off > 0; off >>= 1) ss += __shfl_xor(ss, off, 64);
  float r = rsqrtf(ss * (1.0f / DS) + 1e-6f);
  const float4* nw = (const float4*)(norm_w + ((size_t)head * LL + layer) * DS);
  float4 w0 = nw[lane * 2], w1 = nw[lane * 2 + 1];
  uint4 o;
  o.x = pk2(v0.x * r * w0.x, v0.y * r * w0.y);
  o.y = pk2(v0.z * r * w0.z, v0.w * r * w0.w);
  o.z = pk2(v1.x * r * w1.x, v1.y * r * w1.y);
  o.w = pk2(v1.z * r * w1.z, v1.w * r * w1.w);
  *(uint4*)(xn + (size_t)gw * DS + (size_t)lane * 8) = o;
}

// ---------- GEMM job descriptor ----------
struct GJob {
  const unsigned short* A; int lda; int rstep;
  const unsigned short* Bt; long long b_hstride;   // ldb == K
  const float* bias; int bias_hstride;
  const float* resid; int ldr;
  void* C; int ldc;
  int epi;      // 0: f32 +bias | 1: bf16 gelu(+bias) | 2: f32 +bias+resid
  int gx;       // N-tiles per head
  int tph;      // tiles per head
  int K;
};

// ---------- 256x256 tile, BK=64, 8-wave, 4-phase pipelined bf16 GEMM ----------
// EXACT round-7 core (16x16x32 MFMA, zero bank conflicts, proven schedule):
// P0 read A-lo+B-lo, stage A-hi(t+1), MFMA Q00 | P1 read B-hi, MFMA Q01,
// vmcnt(8) | P2 read A-hi, stage A-lo/B-lo(t+2), MFMA Q11 | P3 stage
// B-hi(t+2), MFMA Q10, vmcnt(8). Runtime GJob (r9-verified) for merged
// two-job launches with per-job K.
__global__ __launch_bounds__(512, 2)
void gemm256_kernel(GJob j0, int n0, GJob j1) {
  __shared__ unsigned short lds[2 * 2 * 256 * 64];  // 128 KiB
  const int tid = threadIdx.x;
  const int lane = tid & 63;
  const int wave = tid >> 6;
  const int wr = wave >> 2, wc = wave & 3;
  const int ntot = gridDim.x;
  int wgid = blockIdx.x;
  { int cpx = ntot >> 3; wgid = (wgid & 7) * cpx + (wgid >> 3); }  // bijective: ntot%8==0
  const GJob J = (wgid < n0) ? j0 : j1;
  const int id = (wgid < n0) ? wgid : wgid - n0;
  const int head = id / J.tph;
  const int rem = id % J.tph;
  const int tn = rem % J.gx, tm = rem / J.gx;
  const int K = J.K;

  // ---- staging addressing (per-lane source, linear LDS dest) ----
  const int l3 = lane >> 3;
  const int gslot = ((lane & 7) ^ l3) * 8;
  const int mbase = wave * 8 + l3;
  const int nbase = (wave >> 2) * 64 + (wave & 3) * 8 + l3;
  const unsigned short* pA = J.A + ((size_t)(tm * 256 + mbase) * J.rstep + head) * J.lda + gslot;
  const unsigned short* pB = J.Bt + (size_t)head * J.b_hstride
                               + (size_t)(tn * 256 + nbase) * K + gslot;
  const size_t aBlk = (size_t)64 * J.rstep * J.lda;

  // ---- fragment read addressing (16x16x32 maps; r7-verified) ----
  const int physk0 = ((lane >> 4) ^ (lane & 7)) * 8;
  const int physk1 = ((4 + (lane >> 4)) ^ (lane & 7)) * 8;
  const int aRow = wr * 128 + (lane & 15);
  const int bRow = wc * 32 + (lane & 15);

  auto stageA = [&](unsigned short* dstA, int h, size_t kels) {
    #pragma unroll
    for (int i = 0; i < 2; ++i)
      __builtin_amdgcn_global_load_lds(
          (gptr_t)(pA + (size_t)(i * 2 + h) * aBlk + kels),
          (lptr_t)(dstA + ((i * 2 + h) * 64 + wave * 8) * 64), 16, 0, 0);
  };
  auto stageB = [&](unsigned short* dstB, int h, size_t kels) {
    #pragma unroll
    for (int i = 0; i < 2; ++i)
      __builtin_amdgcn_global_load_lds(
          (gptr_t)(pB + (size_t)(i * 128 + h * 32) * K + kels),
          (lptr_t)(dstB + (h * 128 + i * 64 + wave * 8) * 64), 16, 0, 0);
  };

  f32x4 acc[8][4];
  #pragma unroll
  for (int i = 0; i < 8; ++i)
    #pragma unroll
    for (int j = 0; j < 4; ++j) acc[i][j] = (f32x4){0.f, 0.f, 0.f, 0.f};
  short8 a[4][2], b[4][2];

  const int T = K >> 6;  // >= 2 for all shapes used
  // ---- prologue: tile0 {A0,B0,B1,A1} + tile1 {A0,B0,B1} ----
  stageA(lds, 0, 0);
  stageB(lds + 16384, 0, 0);
  stageB(lds + 16384, 1, 0);
  stageA(lds, 1, 0);
  stageA(lds + 32768, 0, 64);
  stageB(lds + 32768 + 16384, 0, 64);
  stageB(lds + 32768 + 16384, 1, 64);
  VMCNT8();
  SB();
  BAR();

  for (int t = 0; t < T; ++t) {
    unsigned short* rA = lds + (t & 1) * 32768;
    unsigned short* rB = rA + 16384;
    unsigned short* nA = lds + ((t + 1) & 1) * 32768;
    const size_t k1 = (size_t)(t + 1) * 64;
    const size_t k2 = (size_t)(t + 2) * 64;
    const bool m1 = (t + 1 < T), m2 = (t + 2 < T);

    // ======== P0: read b01 + a-lo; stage A-hi(t+1); MFMA Q00 ========
    #pragma unroll
    for (int j = 0; j < 2; ++j) {
      b[j][0] = *(const short8*)&rB[(bRow + j * 16) * 64 + physk0];
      b[j][1] = *(const short8*)&rB[(bRow + j * 16) * 64 + physk1];
    }
    #pragma unroll
    for (int i = 0; i < 4; ++i) {
      a[i][0] = *(const short8*)&rA[(aRow + i * 16) * 64 + physk0];
      a[i][1] = *(const short8*)&rA[(aRow + i * 16) * 64 + physk1];
    }
    if (m1) stageA(nA, 1, k1);
    __builtin_amdgcn_s_setprio(1);
    #pragma unroll
    for (int i = 0; i < 4; ++i)
      #pragma unroll
      for (int j = 0; j < 2; ++j) {
        acc[i][j] = __builtin_amdgcn_mfma_f32_16x16x32_bf16(a[i][0], b[j][0], acc[i][j], 0, 0, 0);
        acc[i][j] = __builtin_amdgcn_mfma_f32_16x16x32_bf16(a[i][1], b[j][1], acc[i][j], 0, 0, 0);
      }
    __builtin_amdgcn_s_setprio(0);
    BAR();

    // ======== P1: read b23; MFMA Q01; wait A-hi(t) ========
    #pragma unroll
    for (int j = 0; j < 2; ++j) {
      b[2 + j][0] = *(const short8*)&rB[(128 + bRow + j * 16) * 64 + physk0];
      b[2 + j][1] = *(const short8*)&rB[(128 + bRow + j * 16) * 64 + physk1];
    }
    __builtin_amdgcn_s_setprio(1);
    #pragma unroll
    for (int i = 0; i < 4; ++i)
      #pragma unroll
      for (int j = 0; j < 2; ++j) {
        acc[i][2 + j] = __builtin_amdgcn_mfma_f32_16x16x32_bf16(a[i][0], b[2 + j][0], acc[i][2 + j], 0, 0, 0);
        acc[i][2 + j] = __builtin_amdgcn_mfma_f32_16x16x32_bf16(a[i][1], b[2 + j][1], acc[i][2 + j], 0, 0, 0);
      }
    __builtin_amdgcn_s_setprio(0);
    if (m1) { VMCNT8(); } else { VMCNT0(); }
    SB();
    BAR();

    // ======== P2: read a-hi; stage A-lo(t+2)+B-lo(t+2); MFMA Q11 ========
    #pragma unroll
    for (int i = 0; i < 4; ++i) {
      a[i][0] = *(const short8*)&rA[(aRow + (4 + i) * 16) * 64 + physk0];
      a[i][1] = *(const short8*)&rA[(aRow + (4 + i) * 16) * 64 + physk1];
    }
    if (m2) { stageA(rA, 0, k2); stageB(rB, 0, k2); }
    __builtin_amdgcn_s_setprio(1);
    #pragma unroll
    for (int i = 0; i < 4; ++i)
      #pragma unroll
      for (int j = 0; j < 2; ++j) {
        acc[4 + i][2 + j] = __builtin_amdgcn_mfma_f32_16x16x32_bf16(a[i][0], b[2 + j][0], acc[4 + i][2 + j], 0, 0, 0);
        acc[4 + i][2 + j] = __builtin_amdgcn_mfma_f32_16x16x32_bf16(a[i][1], b[2 + j][1], acc[4 + i][2 + j], 0, 0, 0);
      }
    __builtin_amdgcn_s_setprio(0);
    BAR();

    // ======== P3: stage B-hi(t+2); MFMA Q10; wait tile(t+1) ========
    if (m2) stageB(rB, 1, k2);
    __builtin_amdgcn_s_setprio(1);
    #pragma unroll
    for (int i = 0; i < 4; ++i)
      #pragma unroll
      for (int j = 0; j < 2; ++j) {
        acc[4 + i][j] = __builtin_amdgcn_mfma_f32_16x16x32_bf16(a[i][0], b[j][0], acc[4 + i][j], 0, 0, 0);
        acc[4 + i][j] = __builtin_amdgcn_mfma_f32_16x16x32_bf16(a[i][1], b[j][1], acc[4 + i][j], 0, 0, 0);
      }
    __builtin_amdgcn_s_setprio(0);
    if (m2) { VMCNT8(); } else if (m1) { VMCNT2(); }
    SB();
    BAR();
  }

  // ---- epilogue ----
  const float* bptr = J.bias + (size_t)head * J.bias_hstride;
  #pragma unroll
  for (int i = 0; i < 8; ++i) {
    #pragma unroll
    for (int j = 0; j < 4; ++j) {
      #pragma unroll
      for (int r = 0; r < 4; ++r) {
        int rowt = wr * 128 + i * 16 + (lane >> 4) * 4 + r;
        int colt = wc * 64 + j * 16 + (lane & 15);
        int col = tn * 256 + colt;
        size_t crow = (size_t)(tm * 256 + rowt) * J.rstep + head;
        float v = acc[i][j][r] + bptr[col];
        if (J.epi == 1) {
          ((unsigned short*)J.C)[crow * (size_t)J.ldc + col] = f2bf(gelu_exact(v));
        } else if (J.epi == 2) {
          v += J.resid[crow * (size_t)J.ldr + col];
          ((float*)J.C)[crow * (size_t)J.ldc + col] = v;
        } else {
          ((float*)J.C)[crow * (size_t)J.ldc + col] = v;
        }
      }
    }
  }
}

static inline GJob mkjob(const unsigned short* A, int lda, int rstep,
                         const unsigned short* Bt, long long hstride,
                         const float* bias, int bias_h,
                         const float* resid, int ldr,
                         void* C, int ldc, int epi, int gx, int tph, int K) {
  GJob j; j.A = A; j.lda = lda; j.rstep = rstep; j.Bt = Bt; j.b_hstride = hstride;
  j.bias = bias; j.bias_hstride = bias_h; j.resid = resid; j.ldr = ldr;
  j.C = C; j.ldc = ldc; j.epi = epi; j.gx = gx; j.tph = tph; j.K = K;
  return j;
}

extern "C" void kernel_launch(void* const* d_in, const int* in_sizes, int n_in,
                              void* d_out, int out_size, void* d_ws, size_t ws_size,
                              hipStream_t stream) {
  const float* x         = (const float*)d_in[0];
  const float* id_in     = (const float*)d_in[1];
  const float* in_proj_w = (const float*)d_in[2];
  const float* in_proj_b = (const float*)d_in[3];
  const float* norm_w    = (const float*)d_in[4];
  const float* up_w      = (const float*)d_in[5];
  const float* up_b      = (const float*)d_in[6];
  const float* down_w    = (const float*)d_in[7];
  const float* down_b    = (const float*)d_in[8];
  const float* q1_w      = (const float*)d_in[9];
  const float* q1_b      = (const float*)d_in[10];
  const float* q2_w      = (const float*)d_in[11];
  const float* q2_b      = (const float*)d_in[12];
  const float* k1_w      = (const float*)d_in[13];
  const float* k1_b      = (const float*)d_in[14];
  const float* k2_w      = (const float*)d_in[15];
  const float* k2_b      = (const float*)d_in[16];
  float* out = (float*)d_out;

  char* ws = (char*)d_ws;
  unsigned short* x_bf  = (unsigned short*)ws; ws += (size_t)BHROWS * DSTEER * 2;  // 109.1 MB
  unsigned short* id_bf = (unsigned short*)ws; ws += (size_t)BHROWS * DID * 2;     // 8.4 MB
  float*          hbuf  = (float*)ws;          ws += (size_t)BHROWS * DS * 4;      // 67.1 MB
  unsigned short* xn    = (unsigned short*)ws; ws += (size_t)BHROWS * DS * 2;      // 33.6 MB
  unsigned short* hid   = (unsigned short*)ws; ws += (size_t)BHROWS * DHID * 2;    // 134.2 MB
  unsigned short* wbuf  = (unsigned short*)ws; ws += (size_t)HH * DHID * DS * 2;   // 67.1 MB
  size_t base_bytes = (size_t)(ws - (char*)d_ws);
  bool big = ws_size >= base_bytes + (size_t)BHROWS * DHID * 2;   // +134.2 MB for hid_k
  unsigned short* hid_k = big ? (unsigned short*)ws : hid;        // fallback: reuse hid serially

  // parked transposed weights
  unsigned short* q1w_t = wbuf;                                   // 3.41M el
  unsigned short* ipw_t = wbuf + (size_t)DSTEER * 2 * HDQ;        // 27.26M el (30.7M <= 33.55M cap)
  unsigned short* q2w_t = xn;                                     // 2.10M el
  unsigned short* k1w_t = xn + (size_t)2 * HDQ * HDQ;             // 0.26M el (xn corners dead until rms0)
  unsigned short* k2w_t = id_bf;                                  // 2.10M el, into id_bf AFTER k1 consumed it

  // activations -> bf16
  cvt_bf16_kernel<<<2048, 256, 0, stream>>>((const float4*)x, (uint2*)x_bf,
                                            (long)BHROWS * DSTEER / 4);
  cvt_bf16_kernel<<<512, 256, 0, stream>>>((const float4*)id_in, (uint2*)id_bf,
                                           (long)BHROWS * DID / 4);

  // transposes for L1
  transpose_cvt_kernel<<<dim3(2 * HDQ / 64, DSTEER / 32, 1), 256, 0, stream>>>(
      q1_w, 0, q1w_t, 0, DSTEER, 2 * HDQ);
  transpose_cvt_kernel<<<dim3(DS / 64, DSTEER / 32, HH), 256, 0, stream>>>(
      in_proj_w, (long long)DSTEER * DS, ipw_t, (long long)DS * DSTEER, DSTEER, DS);

  // ---- L1: q1 (1024 tiles) + in_proj (256 tiles) ----
  {
    GJob jq1 = mkjob(x_bf, DSTEER, 1, q1w_t, 0, q1_b, 0, nullptr, 0,
                     hid, 2 * HDQ, 1, 8, 1024, DSTEER);
    GJob jip = mkjob(x_bf, DSTEER, HH, ipw_t, (long long)DS * DSTEER, in_proj_b, DS,
                     nullptr, 0, hbuf, DS, 0, 2, 8, DSTEER);
    gemm256_kernel<<<1280, 512, 0, stream>>>(jq1, 1024, jip);
  }

  // transposes for q2/k1 (xn corners; rms0 not yet run)
  transpose_cvt_kernel<<<dim3(HDQ / 64, 2 * HDQ / 32, 1), 256, 0, stream>>>(
      q2_w, 0, q2w_t, 0, 2 * HDQ, HDQ);
  transpose_cvt_kernel<<<dim3(2 * HDQ / 64, DID / 32, 1), 256, 0, stream>>>(
      k1_w, 0, k1w_t, 0, DID, 2 * HDQ);

  GJob jq2 = mkjob(hid, 2 * HDQ, 1, q2w_t, 0, q2_b, 0, nullptr, 0,
                   out + 512, 2560, 0, 4, 512, 2 * HDQ);
  GJob jk1 = mkjob(id_bf, DID, 1, k1w_t, 0, k1_b, 0, nullptr, 0,
                   hid_k, 2 * HDQ, 1, 8, 1024, DID);
  GJob jk2 = mkjob(hid_k, 2 * HDQ, 1, k2w_t, 0, k2_b, 0, nullptr, 0,
                   out + 1536, 2560, 0, 4, 512, 2 * HDQ);

  if (big) {
    // ---- L2: q2 + k1 (k1 -> hid_k, no conflict with q2's hid reads) ----
    gemm256_kernel<<<1536, 512, 0, stream>>>(jq2, 512, jk1);
    rms_scale_kernel<<<8192, 256, 0, stream>>>(hbuf, norm_w, xn, 0);
    transpose_cvt_kernel<<<dim3(DHID / 64, DS / 32, HH), 256, 0, stream>>>(
        up_w, (long long)LL * DS * DHID, wbuf, (long long)DHID * DS, DS, DHID);
    transpose_cvt_kernel<<<dim3(HDQ / 64, 2 * HDQ / 32, 1), 256, 0, stream>>>(
        k2_w, 0, k2w_t, 0, 2 * HDQ, HDQ);   // id_bf dead after L2
    // ---- L3: k2 + up0 (up0 overwrites hid; q2 finished with it in L2) ----
    GJob jup0 = mkjob(xn, DS, HH, wbuf, (long long)DHID * DS, up_b, LL * DHID,
                      nullptr, 0, hid, DHID, 1, 8, 32, DS);
    gemm256_kernel<<<1536, 512, 0, stream>>>(jk2, 512, jup0);
  } else {
    // ---- fallback: serial q2, k1(->hid), k2, rms0, up0 ----
    gemm256_kernel<<<512, 512, 0, stream>>>(jq2, 512, jq2);
    gemm256_kernel<<<1024, 512, 0, stream>>>(jk1, 1024, jk1);
    transpose_cvt_kernel<<<dim3(HDQ / 64, 2 * HDQ / 32, 1), 256, 0, stream>>>(
        k2_w, 0, k2w_t, 0, 2 * HDQ, HDQ);
    gemm256_kernel<<<512, 512, 0, stream>>>(jk2, 512, jk2);
    rms_scale_kernel<<<8192, 256, 0, stream>>>(hbuf, norm_w, xn, 0);
    transpose_cvt_kernel<<<dim3(DHID / 64, DS / 32, HH), 256, 0, stream>>>(
        up_w, (long long)LL * DS * DHID, wbuf, (long long)DHID * DS, DS, DHID);
    GJob jup0 = mkjob(xn, DS, HH, wbuf, (long long)DHID * DS, up_b, LL * DHID,
                      nullptr, 0, hid, DHID, 1, 8, 32, DS);
    gemm256_kernel<<<1024, 512, 0, stream>>>(jup0, 1024, jup0);
  }

  // ---- content chain (layer 0 down, then layers 1,2) ----
  for (int i = 0; i < LL; i++) {
    if (i > 0) {
      rms_scale_kernel<<<8192, 256, 0, stream>>>(hbuf, norm_w, xn, i);
      transpose_cvt_kernel<<<dim3(DHID / 64, DS / 32, HH), 256, 0, stream>>>(
          up_w + (size_t)i * DS * DHID, (long long)LL * DS * DHID,
          wbuf, (long long)DHID * DS, DS, DHID);
      GJob jup = mkjob(xn, DS, HH, wbuf, (long long)DHID * DS,
                       up_b + (size_t)i * DHID, LL * DHID, nullptr, 0,
                       hid, DHID, 1, 8, 32, DS);
      gemm256_kernel<<<1024, 512, 0, stream>>>(jup, 1024, jup);
    }
    transpose_cvt_kernel<<<dim3(DS / 64, DHID / 32, HH), 256, 0, stream>>>(
        down_w + (size_t)i * DHID * DS, (long long)LL * DHID * DS,
        wbuf, (long long)DS * DHID, DHID, DS);
    float* cout = (i < 2) ? hbuf : out;
    int ldc = (i < 2) ? DS : 2560;
    GJob jdn = mkjob(hid, DHID, HH, wbuf, (long long)DS * DHID,
                     down_b + (size_t)i * DS, LL * DS, hbuf, DS,
                     cout, ldc, 2, 2, 8, DHID);
    gemm256_kernel<<<256, 512, 0, stream>>>(jdn, 256, jdn);
  }
}

// Round 11
// 2319.411 us; speedup vs baseline: 1.1128x; 1.1128x over previous
//
#include <hip/hip_runtime.h>
#include <hip/hip_bf16.h>
#include <math.h>

#define HH 32
#define LL 3
#define DS 512
#define DID 128
#define DSTEER 1664
#define DHID 2048
#define HDQ 1024
#define BHROWS 32768

typedef __attribute__((ext_vector_type(8))) short short8;
typedef __attribute__((ext_vector_type(4))) float f32x4;

typedef const __attribute__((address_space(1))) unsigned int* gptr_t;
typedef __attribute__((address_space(3))) unsigned int* lptr_t;

#define BAR() __builtin_amdgcn_s_barrier()
#define SB()  __builtin_amdgcn_sched_barrier(0)
#define VMCNT8() asm volatile("s_waitcnt vmcnt(8)")
#define VMCNT2() asm volatile("s_waitcnt vmcnt(2)")
#define VMCNT0() asm volatile("s_waitcnt vmcnt(0)")

__device__ __forceinline__ unsigned short f2bf(float f) {
  union { float f; unsigned int u; } x; x.f = f;
  unsigned int r = (x.u + 0x7FFFu + ((x.u >> 16) & 1u)) >> 16;
  return (unsigned short)r;
}
__device__ __forceinline__ unsigned int pk2(float a, float b) {
  return (unsigned int)f2bf(a) | ((unsigned int)f2bf(b) << 16);
}
__device__ __forceinline__ float gelu_exact(float v) {
  return 0.5f * v * (1.0f + erff(v * 0.70710678118654752440f));
}

// ---------- fp32 -> bf16 bulk convert ----------
__global__ void cvt_bf16_kernel(const float4* __restrict__ in, uint2* __restrict__ out, long n4) {
  long i = (long)blockIdx.x * blockDim.x + threadIdx.x;
  long stride = (long)gridDim.x * blockDim.x;
  for (; i < n4; i += stride) {
    float4 v = in[i];
    uint2 o; o.x = pk2(v.x, v.y); o.y = pk2(v.z, v.w);
    out[i] = o;
  }
}

// ---------- batched transpose + convert: fp32 [R][C] -> bf16 [C][R] ----------
__global__ void transpose_cvt_kernel(const float* __restrict__ in, long long in_bstride,
                                     unsigned short* __restrict__ out, long long out_bstride,
                                     int R, int C) {
  __shared__ float t[64][33];
  const int r0 = blockIdx.y * 32;
  const int c0 = blockIdx.x * 64;
  const float* bin = in + (long long)blockIdx.z * in_bstride;
  unsigned short* bout = out + (long long)blockIdx.z * out_bstride;
  const int tid = threadIdx.x;
  const int col = tid & 63, rr = tid >> 6;
  #pragma unroll
  for (int j = 0; j < 8; j++) {
    int r = j * 4 + rr;
    t[col][r] = bin[(size_t)(r0 + r) * C + c0 + col];
  }
  __syncthreads();
  const int rq = (tid & 7) * 4;
  const int cc = tid >> 3;
  #pragma unroll
  for (int j = 0; j < 2; j++) {
    int c = j * 32 + cc;
    float v0 = t[c][rq], v1 = t[c][rq + 1], v2 = t[c][rq + 2], v3 = t[c][rq + 3];
    uint2 o; o.x = pk2(v0, v1); o.y = pk2(v2, v3);
    *(uint2*)&bout[(size_t)(c0 + c) * R + r0 + rq] = o;
  }
}

// ---------- RMS-norm + scale -> bf16 ----------
__global__ void rms_scale_kernel(const float* __restrict__ h,
                                 const float* __restrict__ norm_w,
                                 unsigned short* __restrict__ xn, int layer) {
  int gw = (int)((blockIdx.x * blockDim.x + threadIdx.x) >> 6);
  int lane = threadIdx.x & 63;
  if (gw >= BHROWS) return;
  int head = gw & (HH - 1);
  const float4* hr = (const float4*)(h + (size_t)gw * DS);
  float4 v0 = hr[lane * 2], v1 = hr[lane * 2 + 1];
  float ss = v0.x*v0.x + v0.y*v0.y + v0.z*v0.z + v0.w*v0.w
           + v1.x*v1.x + v1.y*v1.y + v1.z*v1.z + v1.w*v1.w;
  #pragma unroll
  for (int off = 32; off > 0; off >>= 1) ss += __shfl_xor(ss, off, 64);
  float r = rsqrtf(ss * (1.0f / DS) + 1e-6f);
  const float4* nw = (const float4*)(norm_w + ((size_t)head * LL + layer) * DS);
  float4 w0 = nw[lane * 2], w1 = nw[lane * 2 + 1];
  uint4 o;
  o.x = pk2(v0.x * r * w0.x, v0.y * r * w0.y);
  o.y = pk2(v0.z * r * w0.z, v0.w * r * w0.w);
  o.z = pk2(v1.x * r * w1.x, v1.y * r * w1.y);
  o.w = pk2(v1.z * r * w1.z, v1.w * r * w1.w);
  *(uint4*)(xn + (size_t)gw * DS + (size_t)lane * 8) = o;
}

// ---------- GEMM job descriptor ----------
struct GJob {
  const unsigned short* A; int lda; int rstep;
  const unsigned short* Bt; long long b_hstride;   // ldb == K
  const float* bias; int bias_hstride;
  const float* resid; int ldr;
  void* C; int ldc;
  int epi;      // 0: f32 +bias | 1: bf16 gelu(+bias) | 2: f32 +bias+resid
  int gx;       // N-tiles per head
  int tph;      // tiles per head
  int K;
};

// ---------- 256x256 tile, BK=64, 8-wave, 4-phase pipelined bf16 GEMM ----------
// EXACT round-7 core. Job split on RAW blockIdx (so both jobs round-robin
// across all 8 XCDs — r10's swizzle-then-split concentrated job0 on 3 XCDs);
// bijective XCD swizzle applied WITHIN each job (job sizes are %8==0).
__global__ __launch_bounds__(512, 2)
void gemm256_kernel(GJob j0, int n0, GJob j1) {
  __shared__ unsigned short lds[2 * 2 * 256 * 64];  // 128 KiB
  const int tid = threadIdx.x;
  const int lane = tid & 63;
  const int wave = tid >> 6;
  const int wr = wave >> 2, wc = wave & 3;
  const int ntot = gridDim.x;
  const int orig = blockIdx.x;
  const bool f0 = orig < n0;
  const GJob J = f0 ? j0 : j1;
  int id = f0 ? orig : orig - n0;
  const int nj = f0 ? n0 : ntot - n0;
  { int cpx = nj >> 3; id = (id & 7) * cpx + (id >> 3); }  // bijective: nj%8==0
  const int head = id / J.tph;
  const int rem = id % J.tph;
  const int tn = rem % J.gx, tm = rem / J.gx;
  const int K = J.K;

  // ---- staging addressing (per-lane source, linear LDS dest) ----
  const int l3 = lane >> 3;
  const int gslot = ((lane & 7) ^ l3) * 8;
  const int mbase = wave * 8 + l3;
  const int nbase = (wave >> 2) * 64 + (wave & 3) * 8 + l3;
  const unsigned short* pA = J.A + ((size_t)(tm * 256 + mbase) * J.rstep + head) * J.lda + gslot;
  const unsigned short* pB = J.Bt + (size_t)head * J.b_hstride
                               + (size_t)(tn * 256 + nbase) * K + gslot;
  const size_t aBlk = (size_t)64 * J.rstep * J.lda;

  // ---- fragment read addressing (16x16x32 maps; r7-verified) ----
  const int physk0 = ((lane >> 4) ^ (lane & 7)) * 8;
  const int physk1 = ((4 + (lane >> 4)) ^ (lane & 7)) * 8;
  const int aRow = wr * 128 + (lane & 15);
  const int bRow = wc * 32 + (lane & 15);

  auto stageA = [&](unsigned short* dstA, int h, size_t kels) {
    #pragma unroll
    for (int i = 0; i < 2; ++i)
      __builtin_amdgcn_global_load_lds(
          (gptr_t)(pA + (size_t)(i * 2 + h) * aBlk + kels),
          (lptr_t)(dstA + ((i * 2 + h) * 64 + wave * 8) * 64), 16, 0, 0);
  };
  auto stageB = [&](unsigned short* dstB, int h, size_t kels) {
    #pragma unroll
    for (int i = 0; i < 2; ++i)
      __builtin_amdgcn_global_load_lds(
          (gptr_t)(pB + (size_t)(i * 128 + h * 32) * K + kels),
          (lptr_t)(dstB + (h * 128 + i * 64 + wave * 8) * 64), 16, 0, 0);
  };

  f32x4 acc[8][4];
  #pragma unroll
  for (int i = 0; i < 8; ++i)
    #pragma unroll
    for (int j = 0; j < 4; ++j) acc[i][j] = (f32x4){0.f, 0.f, 0.f, 0.f};
  short8 a[4][2], b[4][2];

  const int T = K >> 6;
  // ---- prologue: tile0 {A0,B0,B1,A1} + tile1 {A0,B0,B1} ----
  stageA(lds, 0, 0);
  stageB(lds + 16384, 0, 0);
  stageB(lds + 16384, 1, 0);
  stageA(lds, 1, 0);
  stageA(lds + 32768, 0, 64);
  stageB(lds + 32768 + 16384, 0, 64);
  stageB(lds + 32768 + 16384, 1, 64);
  VMCNT8();
  SB();
  BAR();

  for (int t = 0; t < T; ++t) {
    unsigned short* rA = lds + (t & 1) * 32768;
    unsigned short* rB = rA + 16384;
    unsigned short* nA = lds + ((t + 1) & 1) * 32768;
    const size_t k1 = (size_t)(t + 1) * 64;
    const size_t k2 = (size_t)(t + 2) * 64;
    const bool m1 = (t + 1 < T), m2 = (t + 2 < T);

    // ======== P0: read b01 + a-lo; stage A-hi(t+1); MFMA Q00 ========
    #pragma unroll
    for (int j = 0; j < 2; ++j) {
      b[j][0] = *(const short8*)&rB[(bRow + j * 16) * 64 + physk0];
      b[j][1] = *(const short8*)&rB[(bRow + j * 16) * 64 + physk1];
    }
    #pragma unroll
    for (int i = 0; i < 4; ++i) {
      a[i][0] = *(const short8*)&rA[(aRow + i * 16) * 64 + physk0];
      a[i][1] = *(const short8*)&rA[(aRow + i * 16) * 64 + physk1];
    }
    if (m1) stageA(nA, 1, k1);
    __builtin_amdgcn_s_setprio(1);
    #pragma unroll
    for (int i = 0; i < 4; ++i)
      #pragma unroll
      for (int j = 0; j < 2; ++j) {
        acc[i][j] = __builtin_amdgcn_mfma_f32_16x16x32_bf16(a[i][0], b[j][0], acc[i][j], 0, 0, 0);
        acc[i][j] = __builtin_amdgcn_mfma_f32_16x16x32_bf16(a[i][1], b[j][1], acc[i][j], 0, 0, 0);
      }
    __builtin_amdgcn_s_setprio(0);
    BAR();

    // ======== P1: read b23; MFMA Q01; wait A-hi(t) ========
    #pragma unroll
    for (int j = 0; j < 2; ++j) {
      b[2 + j][0] = *(const short8*)&rB[(128 + bRow + j * 16) * 64 + physk0];
      b[2 + j][1] = *(const short8*)&rB[(128 + bRow + j * 16) * 64 + physk1];
    }
    __builtin_amdgcn_s_setprio(1);
    #pragma unroll
    for (int i = 0; i < 4; ++i)
      #pragma unroll
      for (int j = 0; j < 2; ++j) {
        acc[i][2 + j] = __builtin_amdgcn_mfma_f32_16x16x32_bf16(a[i][0], b[2 + j][0], acc[i][2 + j], 0, 0, 0);
        acc[i][2 + j] = __builtin_amdgcn_mfma_f32_16x16x32_bf16(a[i][1], b[2 + j][1], acc[i][2 + j], 0, 0, 0);
      }
    __builtin_amdgcn_s_setprio(0);
    if (m1) { VMCNT8(); } else { VMCNT0(); }
    SB();
    BAR();

    // ======== P2: read a-hi; stage A-lo(t+2)+B-lo(t+2); MFMA Q11 ========
    #pragma unroll
    for (int i = 0; i < 4; ++i) {
      a[i][0] = *(const short8*)&rA[(aRow + (4 + i) * 16) * 64 + physk0];
      a[i][1] = *(const short8*)&rA[(aRow + (4 + i) * 16) * 64 + physk1];
    }
    if (m2) { stageA(rA, 0, k2); stageB(rB, 0, k2); }
    __builtin_amdgcn_s_setprio(1);
    #pragma unroll
    for (int i = 0; i < 4; ++i)
      #pragma unroll
      for (int j = 0; j < 2; ++j) {
        acc[4 + i][2 + j] = __builtin_amdgcn_mfma_f32_16x16x32_bf16(a[i][0], b[2 + j][0], acc[4 + i][2 + j], 0, 0, 0);
        acc[4 + i][2 + j] = __builtin_amdgcn_mfma_f32_16x16x32_bf16(a[i][1], b[2 + j][1], acc[4 + i][2 + j], 0, 0, 0);
      }
    __builtin_amdgcn_s_setprio(0);
    BAR();

    // ======== P3: stage B-hi(t+2); MFMA Q10; wait tile(t+1) ========
    if (m2) stageB(rB, 1, k2);
    __builtin_amdgcn_s_setprio(1);
    #pragma unroll
    for (int i = 0; i < 4; ++i)
      #pragma unroll
      for (int j = 0; j < 2; ++j) {
        acc[4 + i][j] = __builtin_amdgcn_mfma_f32_16x16x32_bf16(a[i][0], b[j][0], acc[4 + i][j], 0, 0, 0);
        acc[4 + i][j] = __builtin_amdgcn_mfma_f32_16x16x32_bf16(a[i][1], b[j][1], acc[4 + i][j], 0, 0, 0);
      }
    __builtin_amdgcn_s_setprio(0);
    if (m2) { VMCNT8(); } else if (m1) { VMCNT2(); }
    SB();
    BAR();
  }

  // ---- epilogue ----
  const float* bptr = J.bias + (size_t)head * J.bias_hstride;
  #pragma unroll
  for (int i = 0; i < 8; ++i) {
    #pragma unroll
    for (int j = 0; j < 4; ++j) {
      #pragma unroll
      for (int r = 0; r < 4; ++r) {
        int rowt = wr * 128 + i * 16 + (lane >> 4) * 4 + r;
        int colt = wc * 64 + j * 16 + (lane & 15);
        int col = tn * 256 + colt;
        size_t crow = (size_t)(tm * 256 + rowt) * J.rstep + head;
        float v = acc[i][j][r] + bptr[col];
        if (J.epi == 1) {
          ((unsigned short*)J.C)[crow * (size_t)J.ldc + col] = f2bf(gelu_exact(v));
        } else if (J.epi == 2) {
          v += J.resid[crow * (size_t)J.ldr + col];
          ((float*)J.C)[crow * (size_t)J.ldc + col] = v;
        } else {
          ((float*)J.C)[crow * (size_t)J.ldc + col] = v;
        }
      }
    }
  }
}

static inline GJob mkjob(const unsigned short* A, int lda, int rstep,
                         const unsigned short* Bt, long long hstride,
                         const float* bias, int bias_h,
                         const float* resid, int ldr,
                         void* C, int ldc, int epi, int gx, int tph, int K) {
  GJob j; j.A = A; j.lda = lda; j.rstep = rstep; j.Bt = Bt; j.b_hstride = hstride;
  j.bias = bias; j.bias_hstride = bias_h; j.resid = resid; j.ldr = ldr;
  j.C = C; j.ldc = ldc; j.epi = epi; j.gx = gx; j.tph = tph; j.K = K;
  return j;
}

extern "C" void kernel_launch(void* const* d_in, const int* in_sizes, int n_in,
                              void* d_out, int out_size, void* d_ws, size_t ws_size,
                              hipStream_t stream) {
  const float* x         = (const float*)d_in[0];
  const float* id_in     = (const float*)d_in[1];
  const float* in_proj_w = (const float*)d_in[2];
  const float* in_proj_b = (const float*)d_in[3];
  const float* norm_w    = (const float*)d_in[4];
  const float* up_w      = (const float*)d_in[5];
  const float* up_b      = (const float*)d_in[6];
  const float* down_w    = (const float*)d_in[7];
  const float* down_b    = (const float*)d_in[8];
  const float* q1_w      = (const float*)d_in[9];
  const float* q1_b      = (const float*)d_in[10];
  const float* q2_w      = (const float*)d_in[11];
  const float* q2_b      = (const float*)d_in[12];
  const float* k1_w      = (const float*)d_in[13];
  const float* k1_b      = (const float*)d_in[14];
  const float* k2_w      = (const float*)d_in[15];
  const float* k2_b      = (const float*)d_in[16];
  float* out = (float*)d_out;

  char* ws = (char*)d_ws;
  unsigned short* x_bf  = (unsigned short*)ws; ws += (size_t)BHROWS * DSTEER * 2;  // 109.1 MB
  unsigned short* id_bf = (unsigned short*)ws; ws += (size_t)BHROWS * DID * 2;     // 8.4 MB
  float*          hbuf  = (float*)ws;          ws += (size_t)BHROWS * DS * 4;      // 67.1 MB
  unsigned short* xn    = (unsigned short*)ws; ws += (size_t)BHROWS * DS * 2;      // 33.6 MB
  unsigned short* hid   = (unsigned short*)ws; ws += (size_t)BHROWS * DHID * 2;    // 134.2 MB
  unsigned short* wbuf  = (unsigned short*)ws; ws += (size_t)HH * DHID * DS * 2;   // 67.1 MB
  size_t base_bytes = (size_t)(ws - (char*)d_ws);
  bool big = ws_size >= base_bytes + (size_t)BHROWS * DHID * 2;   // +134.2 MB hid_k
  unsigned short* hid_k = big ? (unsigned short*)ws : hid;

  // parked transposed weights
  unsigned short* q1w_t = wbuf;                                   // 3.41M el
  unsigned short* ipw_t = wbuf + (size_t)DSTEER * 2 * HDQ;        // +27.26M el (<= 33.55M)
  unsigned short* q2w_t = wbuf;                                   // after L1 (wbuf dead)
  unsigned short* k1w_t = xn;                                     // parked between up0 and rms1
  unsigned short* k2w_t = id_bf;                                  // parked after k1 consumed id_bf

  // activations -> bf16
  cvt_bf16_kernel<<<2048, 256, 0, stream>>>((const float4*)x, (uint2*)x_bf,
                                            (long)BHROWS * DSTEER / 4);
  cvt_bf16_kernel<<<512, 256, 0, stream>>>((const float4*)id_in, (uint2*)id_bf,
                                           (long)BHROWS * DID / 4);

  // transposes for L1
  transpose_cvt_kernel<<<dim3(2 * HDQ / 64, DSTEER / 32, 1), 256, 0, stream>>>(
      q1_w, 0, q1w_t, 0, DSTEER, 2 * HDQ);
  transpose_cvt_kernel<<<dim3(DS / 64, DSTEER / 32, HH), 256, 0, stream>>>(
      in_proj_w, (long long)DSTEER * DS, ipw_t, (long long)DS * DSTEER, DSTEER, DS);

  // ---- L1: q1 (1024, T=26) + in_proj (256, T=26) ----
  {
    GJob jq1 = mkjob(x_bf, DSTEER, 1, q1w_t, 0, q1_b, 0, nullptr, 0,
                     hid, 2 * HDQ, 1, 8, 1024, DSTEER);
    GJob jip = mkjob(x_bf, DSTEER, HH, ipw_t, (long long)DS * DSTEER, in_proj_b, DS,
                     nullptr, 0, hbuf, DS, 0, 2, 8, DSTEER);
    gemm256_kernel<<<1280, 512, 0, stream>>>(jq1, 1024, jip);
  }

  // rms0 + q2 weights (wbuf dead after L1)
  rms_scale_kernel<<<8192, 256, 0, stream>>>(hbuf, norm_w, xn, 0);
  transpose_cvt_kernel<<<dim3(HDQ / 64, 2 * HDQ / 32, 1), 256, 0, stream>>>(
      q2_w, 0, q2w_t, 0, 2 * HDQ, HDQ);

  // ---- q2 serial (512, T=32); hid free afterwards ----
  {
    GJob jq2 = mkjob(hid, 2 * HDQ, 1, q2w_t, 0, q2_b, 0, nullptr, 0,
                     out + 512, 2560, 0, 4, 512, 2 * HDQ);
    gemm256_kernel<<<512, 512, 0, stream>>>(jq2, 512, jq2);
  }

  GJob jk1 = mkjob(id_bf, DID, 1, k1w_t, 0, k1_b, 0, nullptr, 0,
                   hid_k, 2 * HDQ, 1, 8, 1024, DID);
  GJob jk2a = mkjob(hid_k, 2 * HDQ, 1, k2w_t, 0, k2_b, 0, nullptr, 0,
                    out + 1536, 2560, 0, 4, 512, 2 * HDQ);
  GJob jk2b = mkjob(hid_k + (size_t)16384 * 2 * HDQ, 2 * HDQ, 1, k2w_t, 0, k2_b, 0,
                    nullptr, 0, out + 1536 + (size_t)16384 * 2560, 2560, 0, 4, 512, 2 * HDQ);

  for (int i = 0; i < LL; i++) {
    if (i > 0) rms_scale_kernel<<<8192, 256, 0, stream>>>(hbuf, norm_w, xn, i);
    // up weights -> wbuf; up_i -> hid
    transpose_cvt_kernel<<<dim3(DHID / 64, DS / 32, HH), 256, 0, stream>>>(
        up_w + (size_t)i * DS * DHID, (long long)LL * DS * DHID,
        wbuf, (long long)DHID * DS, DS, DHID);
    GJob jup = mkjob(xn, DS, HH, wbuf, (long long)DHID * DS,
                     up_b + (size_t)i * DHID, LL * DHID, nullptr, 0,
                     hid, DHID, 1, 8, 32, DS);
    gemm256_kernel<<<1024, 512, 0, stream>>>(jup, 1024, jup);
    // down weights -> wbuf (+ k-path weight transposes at their safe points)
    if (i == 0 && big) {
      transpose_cvt_kernel<<<dim3(2 * HDQ / 64, DID / 32, 1), 256, 0, stream>>>(
          k1_w, 0, k1w_t, 0, DID, 2 * HDQ);   // xn dead (up0 done) until rms1
    }
    transpose_cvt_kernel<<<dim3(DS / 64, DHID / 32, HH), 256, 0, stream>>>(
        down_w + (size_t)i * DHID * DS, (long long)LL * DHID * DS,
        wbuf, (long long)DS * DHID, DHID, DS);
    float* cout = (i < 2) ? hbuf : out;
    int ldc = (i < 2) ? DS : 2560;
    GJob jdn = mkjob(hid, DHID, HH, wbuf, (long long)DS * DHID,
                     down_b + (size_t)i * DS, LL * DS, hbuf, DS,
                     cout, ldc, 2, 2, 8, DHID);
    if (big) {
      if (i == 0) {
        // L3: down0 (256, T=32) + k1 (1024, T=2) -> hbuf, hid_k
        gemm256_kernel<<<1280, 512, 0, stream>>>(jdn, 256, jk1);
        transpose_cvt_kernel<<<dim3(HDQ / 64, 2 * HDQ / 32, 1), 256, 0, stream>>>(
            k2_w, 0, k2w_t, 0, 2 * HDQ, HDQ);  // id_bf dead after k1
      } else if (i == 1) {
        // L4: down1 (256) + k2a (256)
        gemm256_kernel<<<512, 512, 0, stream>>>(jdn, 256, jk2a);
      } else {
        // L5: down2 (256) + k2b (256)
        gemm256_kernel<<<512, 512, 0, stream>>>(jdn, 256, jk2b);
      }
    } else {
      gemm256_kernel<<<256, 512, 0, stream>>>(jdn, 256, jdn);
    }
  }

  if (!big) {
    // fallback: serial k path using hid (free after q2; content chain reused it,
    // so k path must run after content chain with hid_k == hid)
    transpose_cvt_kernel<<<dim3(2 * HDQ / 64, DID / 32, 1), 256, 0, stream>>>(
        k1_w, 0, k1w_t, 0, DID, 2 * HDQ);
    gemm256_kernel<<<1024, 512, 0, stream>>>(jk1, 1024, jk1);
    transpose_cvt_kernel<<<dim3(HDQ / 64, 2 * HDQ / 32, 1), 256, 0, stream>>>(
        k2_w, 0, k2w_t, 0, 2 * HDQ, HDQ);
    gemm256_kernel<<<512, 512, 0, stream>>>(jk2a, 256, jk2b);
  }
}

// Round 12
// 1613.995 us; speedup vs baseline: 1.5991x; 1.4371x over previous
//
#include <hip/hip_runtime.h>
#include <hip/hip_bf16.h>
#include <math.h>

#define HH 32
#define LL 3
#define DS 512
#define DID 128
#define DSTEER 1664
#define DHID 2048
#define HDQ 1024
#define BHROWS 32768

typedef __attribute__((ext_vector_type(8))) short short8;
typedef __attribute__((ext_vector_type(4))) float f32x4;

typedef const __attribute__((address_space(1))) unsigned int* gptr_t;
typedef __attribute__((address_space(3))) unsigned int* lptr_t;

#define BAR() __builtin_amdgcn_s_barrier()
#define SB()  __builtin_amdgcn_sched_barrier(0)
#define VMCNT8() asm volatile("s_waitcnt vmcnt(8)")
#define VMCNT2() asm volatile("s_waitcnt vmcnt(2)")
#define VMCNT0() asm volatile("s_waitcnt vmcnt(0)")

__device__ __forceinline__ unsigned short f2bf(float f) {
  union { float f; unsigned int u; } x; x.f = f;
  unsigned int r = (x.u + 0x7FFFu + ((x.u >> 16) & 1u)) >> 16;
  return (unsigned short)r;
}
__device__ __forceinline__ unsigned int pk2(float a, float b) {
  return (unsigned int)f2bf(a) | ((unsigned int)f2bf(b) << 16);
}
__device__ __forceinline__ float gelu_exact(float v) {
  return 0.5f * v * (1.0f + erff(v * 0.70710678118654752440f));
}

// ---------- fp32 -> bf16 bulk convert ----------
__global__ void cvt_bf16_kernel(const float4* __restrict__ in, uint2* __restrict__ out, long n4) {
  long i = (long)blockIdx.x * blockDim.x + threadIdx.x;
  long stride = (long)gridDim.x * blockDim.x;
  for (; i < n4; i += stride) {
    float4 v = in[i];
    uint2 o; o.x = pk2(v.x, v.y); o.y = pk2(v.z, v.w);
    out[i] = o;
  }
}

// ---------- batched transpose + convert: fp32 [R][C] -> bf16 [C][R] ----------
__global__ void transpose_cvt_kernel(const float* __restrict__ in, long long in_bstride,
                                     unsigned short* __restrict__ out, long long out_bstride,
                                     int R, int C) {
  __shared__ float t[64][33];
  const int r0 = blockIdx.y * 32;
  const int c0 = blockIdx.x * 64;
  const float* bin = in + (long long)blockIdx.z * in_bstride;
  unsigned short* bout = out + (long long)blockIdx.z * out_bstride;
  const int tid = threadIdx.x;
  const int col = tid & 63, rr = tid >> 6;
  #pragma unroll
  for (int j = 0; j < 8; j++) {
    int r = j * 4 + rr;
    t[col][r] = bin[(size_t)(r0 + r) * C + c0 + col];
  }
  __syncthreads();
  const int rq = (tid & 7) * 4;
  const int cc = tid >> 3;
  #pragma unroll
  for (int j = 0; j < 2; j++) {
    int c = j * 32 + cc;
    float v0 = t[c][rq], v1 = t[c][rq + 1], v2 = t[c][rq + 2], v3 = t[c][rq + 3];
    uint2 o; o.x = pk2(v0, v1); o.y = pk2(v2, v3);
    *(uint2*)&bout[(size_t)(c0 + c) * R + r0 + rq] = o;
  }
}

// ---------- RMS-norm + scale -> bf16 (HEAD-MAJOR rows: gw = h*1024 + b) ----------
__global__ void rms_scale_kernel(const float* __restrict__ h,
                                 const float* __restrict__ norm_w,
                                 unsigned short* __restrict__ xn, int layer) {
  int gw = (int)((blockIdx.x * blockDim.x + threadIdx.x) >> 6);
  int lane = threadIdx.x & 63;
  if (gw >= BHROWS) return;
  int head = gw >> 10;                       // head-major layout
  const float4* hr = (const float4*)(h + (size_t)gw * DS);
  float4 v0 = hr[lane * 2], v1 = hr[lane * 2 + 1];
  float ss = v0.x*v0.x + v0.y*v0.y + v0.z*v0.z + v0.w*v0.w
           + v1.x*v1.x + v1.y*v1.y + v1.z*v1.z + v1.w*v1.w;
  #pragma unroll
  for (int off = 32; off > 0; off >>= 1) ss += __shfl_xor(ss, off, 64);
  float r = rsqrtf(ss * (1.0f / DS) + 1e-6f);
  const float4* nw = (const float4*)(norm_w + ((size_t)head * LL + layer) * DS);
  float4 w0 = nw[lane * 2], w1 = nw[lane * 2 + 1];
  uint4 o;
  o.x = pk2(v0.x * r * w0.x, v0.y * r * w0.y);
  o.y = pk2(v0.z * r * w0.z, v0.w * r * w0.w);
  o.z = pk2(v1.x * r * w1.x, v1.y * r * w1.y);
  o.w = pk2(v1.z * r * w1.z, v1.w * r * w1.w);
  *(uint4*)(xn + (size_t)gw * DS + (size_t)lane * 8) = o;
}

// ---------- 256x256 tile, BK=64, 8-wave, 4-phase pipelined bf16 GEMM ----------
// EXACT round-7 core (single job, serial launches — merging refuted r9-r11).
// Generalized addressing: A row r of head h at A + h*a_hstride + r*a_rstride;
// C element (r,col) at C + h*c_hstride + r*c_rstride + col; resid likewise.
template<int EPI>
__global__ __launch_bounds__(512, 2)
void gemm256_kernel(const unsigned short* __restrict__ A, long long a_hstride, long long a_rstride,
                    const unsigned short* __restrict__ Bt, long long b_hstride,
                    const float* __restrict__ bias, int bias_hstride,
                    const float* __restrict__ resid, long long r_hstride, long long r_rstride,
                    void* __restrict__ Cv, long long c_hstride, long long c_rstride,
                    int gx, int tph, int K) {
  __shared__ unsigned short lds[2 * 2 * 256 * 64];  // 128 KiB
  const int tid = threadIdx.x;
  const int lane = tid & 63;
  const int wave = tid >> 6;
  const int wr = wave >> 2, wc = wave & 3;
  const int ntot = gridDim.x;
  int id = blockIdx.x;
  { int cpx = ntot >> 3; id = (id & 7) * cpx + (id >> 3); }  // bijective: ntot%8==0
  const int head = id / tph;
  const int rem = id % tph;
  const int tn = rem % gx, tm = rem / gx;

  // ---- staging addressing (per-lane source, linear LDS dest) ----
  const int l3 = lane >> 3;
  const int gslot = ((lane & 7) ^ l3) * 8;
  const int mbase = wave * 8 + l3;
  const int nbase = (wave >> 2) * 64 + (wave & 3) * 8 + l3;
  const unsigned short* pA = A + (size_t)head * a_hstride
                               + (size_t)(tm * 256 + mbase) * a_rstride + gslot;
  const unsigned short* pB = Bt + (size_t)head * b_hstride
                               + (size_t)(tn * 256 + nbase) * K + gslot;
  const size_t aBlk = (size_t)64 * a_rstride;

  // ---- fragment read addressing (16x16x32 maps; r7-verified) ----
  const int physk0 = ((lane >> 4) ^ (lane & 7)) * 8;
  const int physk1 = ((4 + (lane >> 4)) ^ (lane & 7)) * 8;
  const int aRow = wr * 128 + (lane & 15);
  const int bRow = wc * 32 + (lane & 15);

  auto stageA = [&](unsigned short* dstA, int h, size_t kels) {
    #pragma unroll
    for (int i = 0; i < 2; ++i)
      __builtin_amdgcn_global_load_lds(
          (gptr_t)(pA + (size_t)(i * 2 + h) * aBlk + kels),
          (lptr_t)(dstA + ((i * 2 + h) * 64 + wave * 8) * 64), 16, 0, 0);
  };
  auto stageB = [&](unsigned short* dstB, int h, size_t kels) {
    #pragma unroll
    for (int i = 0; i < 2; ++i)
      __builtin_amdgcn_global_load_lds(
          (gptr_t)(pB + (size_t)(i * 128 + h * 32) * K + kels),
          (lptr_t)(dstB + (h * 128 + i * 64 + wave * 8) * 64), 16, 0, 0);
  };

  f32x4 acc[8][4];
  #pragma unroll
  for (int i = 0; i < 8; ++i)
    #pragma unroll
    for (int j = 0; j < 4; ++j) acc[i][j] = (f32x4){0.f, 0.f, 0.f, 0.f};
  short8 a[4][2], b[4][2];

  const int T = K >> 6;
  // ---- prologue: tile0 {A0,B0,B1,A1} + tile1 {A0,B0,B1} ----
  stageA(lds, 0, 0);
  stageB(lds + 16384, 0, 0);
  stageB(lds + 16384, 1, 0);
  stageA(lds, 1, 0);
  stageA(lds + 32768, 0, 64);
  stageB(lds + 32768 + 16384, 0, 64);
  stageB(lds + 32768 + 16384, 1, 64);
  VMCNT8();
  SB();
  BAR();

  for (int t = 0; t < T; ++t) {
    unsigned short* rA = lds + (t & 1) * 32768;
    unsigned short* rB = rA + 16384;
    unsigned short* nA = lds + ((t + 1) & 1) * 32768;
    const size_t k1 = (size_t)(t + 1) * 64;
    const size_t k2 = (size_t)(t + 2) * 64;
    const bool m1 = (t + 1 < T), m2 = (t + 2 < T);

    // ======== P0: read b01 + a-lo; stage A-hi(t+1); MFMA Q00 ========
    #pragma unroll
    for (int j = 0; j < 2; ++j) {
      b[j][0] = *(const short8*)&rB[(bRow + j * 16) * 64 + physk0];
      b[j][1] = *(const short8*)&rB[(bRow + j * 16) * 64 + physk1];
    }
    #pragma unroll
    for (int i = 0; i < 4; ++i) {
      a[i][0] = *(const short8*)&rA[(aRow + i * 16) * 64 + physk0];
      a[i][1] = *(const short8*)&rA[(aRow + i * 16) * 64 + physk1];
    }
    if (m1) stageA(nA, 1, k1);
    __builtin_amdgcn_s_setprio(1);
    #pragma unroll
    for (int i = 0; i < 4; ++i)
      #pragma unroll
      for (int j = 0; j < 2; ++j) {
        acc[i][j] = __builtin_amdgcn_mfma_f32_16x16x32_bf16(a[i][0], b[j][0], acc[i][j], 0, 0, 0);
        acc[i][j] = __builtin_amdgcn_mfma_f32_16x16x32_bf16(a[i][1], b[j][1], acc[i][j], 0, 0, 0);
      }
    __builtin_amdgcn_s_setprio(0);
    BAR();

    // ======== P1: read b23; MFMA Q01; wait A-hi(t) ========
    #pragma unroll
    for (int j = 0; j < 2; ++j) {
      b[2 + j][0] = *(const short8*)&rB[(128 + bRow + j * 16) * 64 + physk0];
      b[2 + j][1] = *(const short8*)&rB[(128 + bRow + j * 16) * 64 + physk1];
    }
    __builtin_amdgcn_s_setprio(1);
    #pragma unroll
    for (int i = 0; i < 4; ++i)
      #pragma unroll
      for (int j = 0; j < 2; ++j) {
        acc[i][2 + j] = __builtin_amdgcn_mfma_f32_16x16x32_bf16(a[i][0], b[2 + j][0], acc[i][2 + j], 0, 0, 0);
        acc[i][2 + j] = __builtin_amdgcn_mfma_f32_16x16x32_bf16(a[i][1], b[2 + j][1], acc[i][2 + j], 0, 0, 0);
      }
    __builtin_amdgcn_s_setprio(0);
    if (m1) { VMCNT8(); } else { VMCNT0(); }
    SB();
    BAR();

    // ======== P2: read a-hi; stage A-lo(t+2)+B-lo(t+2); MFMA Q11 ========
    #pragma unroll
    for (int i = 0; i < 4; ++i) {
      a[i][0] = *(const short8*)&rA[(aRow + (4 + i) * 16) * 64 + physk0];
      a[i][1] = *(const short8*)&rA[(aRow + (4 + i) * 16) * 64 + physk1];
    }
    if (m2) { stageA(rA, 0, k2); stageB(rB, 0, k2); }
    __builtin_amdgcn_s_setprio(1);
    #pragma unroll
    for (int i = 0; i < 4; ++i)
      #pragma unroll
      for (int j = 0; j < 2; ++j) {
        acc[4 + i][2 + j] = __builtin_amdgcn_mfma_f32_16x16x32_bf16(a[i][0], b[2 + j][0], acc[4 + i][2 + j], 0, 0, 0);
        acc[4 + i][2 + j] = __builtin_amdgcn_mfma_f32_16x16x32_bf16(a[i][1], b[2 + j][1], acc[4 + i][2 + j], 0, 0, 0);
      }
    __builtin_amdgcn_s_setprio(0);
    BAR();

    // ======== P3: stage B-hi(t+2); MFMA Q10; wait tile(t+1) ========
    if (m2) stageB(rB, 1, k2);
    __builtin_amdgcn_s_setprio(1);
    #pragma unroll
    for (int i = 0; i < 4; ++i)
      #pragma unroll
      for (int j = 0; j < 2; ++j) {
        acc[4 + i][j] = __builtin_amdgcn_mfma_f32_16x16x32_bf16(a[i][0], b[j][0], acc[4 + i][j], 0, 0, 0);
        acc[4 + i][j] = __builtin_amdgcn_mfma_f32_16x16x32_bf16(a[i][1], b[j][1], acc[4 + i][j], 0, 0, 0);
      }
    __builtin_amdgcn_s_setprio(0);
    if (m2) { VMCNT8(); } else if (m1) { VMCNT2(); }
    SB();
    BAR();
  }

  // ---- epilogue ----
  const float* bptr = bias + (size_t)head * bias_hstride;
  #pragma unroll
  for (int i = 0; i < 8; ++i) {
    #pragma unroll
    for (int j = 0; j < 4; ++j) {
      #pragma unroll
      for (int r = 0; r < 4; ++r) {
        int rowt = wr * 128 + i * 16 + (lane >> 4) * 4 + r;
        int colt = wc * 64 + j * 16 + (lane & 15);
        int col = tn * 256 + colt;
        size_t row = (size_t)(tm * 256 + rowt);
        size_t cidx = (size_t)head * c_hstride + row * c_rstride + col;
        float v = acc[i][j][r] + bptr[col];
        if (EPI == 1) {
          ((unsigned short*)Cv)[cidx] = f2bf(gelu_exact(v));
        } else if (EPI == 2) {
          v += resid[(size_t)head * r_hstride + row * r_rstride + col];
          ((float*)Cv)[cidx] = v;
        } else {
          ((float*)Cv)[cidx] = v;
        }
      }
    }
  }
}

extern "C" void kernel_launch(void* const* d_in, const int* in_sizes, int n_in,
                              void* d_out, int out_size, void* d_ws, size_t ws_size,
                              hipStream_t stream) {
  const float* x         = (const float*)d_in[0];
  const float* id_in     = (const float*)d_in[1];
  const float* in_proj_w = (const float*)d_in[2];
  const float* in_proj_b = (const float*)d_in[3];
  const float* norm_w    = (const float*)d_in[4];
  const float* up_w      = (const float*)d_in[5];
  const float* up_b      = (const float*)d_in[6];
  const float* down_w    = (const float*)d_in[7];
  const float* down_b    = (const float*)d_in[8];
  const float* q1_w      = (const float*)d_in[9];
  const float* q1_b      = (const float*)d_in[10];
  const float* q2_w      = (const float*)d_in[11];
  const float* q2_b      = (const float*)d_in[12];
  const float* k1_w      = (const float*)d_in[13];
  const float* k1_b      = (const float*)d_in[14];
  const float* k2_w      = (const float*)d_in[15];
  const float* k2_b      = (const float*)d_in[16];
  float* out = (float*)d_out;

  char* ws = (char*)d_ws;
  unsigned short* x_bf  = (unsigned short*)ws; ws += (size_t)BHROWS * DSTEER * 2;  // 109 MB
  unsigned short* id_bf = (unsigned short*)ws; ws += (size_t)BHROWS * DID * 2;     // 8.4 MB
  float*          hbuf  = (float*)ws;          ws += (size_t)BHROWS * DS * 4;      // 67 MB (head-major)
  unsigned short* xn    = (unsigned short*)ws; ws += (size_t)BHROWS * DS * 2;      // 33.5 MB (head-major)
  unsigned short* hid   = (unsigned short*)ws; ws += (size_t)BHROWS * DHID * 2;    // 134 MB
  unsigned short* wbuf  = (unsigned short*)ws; ws += (size_t)HH * DHID * DS * 2;   // 67 MB (reused)

  // activations -> bf16 (row order preserved: b*32+h)
  cvt_bf16_kernel<<<2048, 256, 0, stream>>>((const float4*)x, (uint2*)x_bf,
                                            (long)BHROWS * DSTEER / 4);
  cvt_bf16_kernel<<<512, 256, 0, stream>>>((const float4*)id_in, (uint2*)id_bf,
                                           (long)BHROWS * DID / 4);

  // ---- q path (flat rows; C row order = A row order = out row order) ----
  transpose_cvt_kernel<<<dim3(2 * HDQ / 64, DSTEER / 32, 1), 256, 0, stream>>>(
      q1_w, 0, wbuf, 0, DSTEER, 2 * HDQ);
  gemm256_kernel<1><<<1024, 512, 0, stream>>>(
      x_bf, 0, DSTEER, wbuf, 0, q1_b, 0, nullptr, 0, 0,
      hid, 0, 2 * HDQ, 8, 1024, DSTEER);
  transpose_cvt_kernel<<<dim3(HDQ / 64, 2 * HDQ / 32, 1), 256, 0, stream>>>(
      q2_w, 0, wbuf, 0, 2 * HDQ, HDQ);
  gemm256_kernel<0><<<512, 512, 0, stream>>>(
      hid, 0, 2 * HDQ, wbuf, 0, q2_b, 0, nullptr, 0, 0,
      out + 512, 0, 2560, 4, 512, 2 * HDQ);

  // ---- k path ----
  transpose_cvt_kernel<<<dim3(2 * HDQ / 64, DID / 32, 1), 256, 0, stream>>>(
      k1_w, 0, wbuf, 0, DID, 2 * HDQ);
  gemm256_kernel<1><<<1024, 512, 0, stream>>>(
      id_bf, 0, DID, wbuf, 0, k1_b, 0, nullptr, 0, 0,
      hid, 0, 2 * HDQ, 8, 1024, DID);
  transpose_cvt_kernel<<<dim3(HDQ / 64, 2 * HDQ / 32, 1), 256, 0, stream>>>(
      k2_w, 0, wbuf, 0, 2 * HDQ, HDQ);
  gemm256_kernel<0><<<512, 512, 0, stream>>>(
      hid, 0, 2 * HDQ, wbuf, 0, k2_b, 0, nullptr, 0, 0,
      out + 1536, 0, 2560, 4, 512, 2 * HDQ);

  // ---- content: in_proj (A interleaved input; C -> hbuf HEAD-MAJOR) ----
  transpose_cvt_kernel<<<dim3(DS / 64, DSTEER / 32, HH), 256, 0, stream>>>(
      in_proj_w, (long long)DSTEER * DS, wbuf, (long long)DS * DSTEER, DSTEER, DS);
  gemm256_kernel<0><<<256, 512, 0, stream>>>(
      x_bf, DSTEER, (long long)32 * DSTEER, wbuf, (long long)DS * DSTEER,
      in_proj_b, DS, nullptr, 0, 0,
      hbuf, (long long)1024 * DS, DS, 2, 8, DSTEER);

  for (int i = 0; i < LL; i++) {
    rms_scale_kernel<<<8192, 256, 0, stream>>>(hbuf, norm_w, xn, i);
    transpose_cvt_kernel<<<dim3(DHID / 64, DS / 32, HH), 256, 0, stream>>>(
        up_w + (size_t)i * DS * DHID, (long long)LL * DS * DHID,
        wbuf, (long long)DHID * DS, DS, DHID);
    // up: A = xn head-major (contiguous rows), C = hid head-major
    gemm256_kernel<1><<<1024, 512, 0, stream>>>(
        xn, (long long)1024 * DS, DS, wbuf, (long long)DHID * DS,
        up_b + (size_t)i * DHID, LL * DHID, nullptr, 0, 0,
        hid, (long long)1024 * DHID, DHID, 8, 32, DS);
    transpose_cvt_kernel<<<dim3(DS / 64, DHID / 32, HH), 256, 0, stream>>>(
        down_w + (size_t)i * DHID * DS, (long long)LL * DHID * DS,
        wbuf, (long long)DS * DHID, DHID, DS);
    // down: A = hid head-major; resid = hbuf head-major;
    // C: layers 0,1 -> hbuf head-major; layer 2 -> out (interleaved rows b*32+h)
    if (i < 2) {
      gemm256_kernel<2><<<256, 512, 0, stream>>>(
          hid, (long long)1024 * DHID, DHID, wbuf, (long long)DS * DHID,
          down_b + (size_t)i * DS, LL * DS,
          hbuf, (long long)1024 * DS, DS,
          hbuf, (long long)1024 * DS, DS, 2, 8, DHID);
    } else {
      gemm256_kernel<2><<<256, 512, 0, stream>>>(
          hid, (long long)1024 * DHID, DHID, wbuf, (long long)DS * DHID,
          down_b + (size_t)i * DS, LL * DS,
          hbuf, (long long)1024 * DS, DS,
          out, 2560, (long long)32 * 2560, 2, 8, DHID);
    }
  }
}